// Round 1
// baseline (279.639 us; speedup 1.0000x reference)
//
#include <hip/hip_runtime.h>
#include <hip/hip_bf16.h>

typedef __attribute__((ext_vector_type(8))) short bf16x8;
typedef __attribute__((ext_vector_type(4))) float f32x4;
typedef __attribute__((ext_vector_type(4))) int int4v;

#define NB 2
#define NN 8192
#define NC 64

// ws layout (bytes):
//   [0, 2MB)      qb : bf16 [B][N][C]
//   [2MB, 4MB)    qt : bf16 [B][C][N]
//   [4MB, 4MB+8)  maxn : uint32[2] (per-batch max row norm, float bits)

// ---------------- prep: fp32 -> bf16 row-major + transposed + row-norm max ----------------
__global__ __launch_bounds__(256) void prep_kernel(
        const float* __restrict__ x,
        __hip_bfloat16* __restrict__ qb,
        __hip_bfloat16* __restrict__ qt,
        unsigned int* __restrict__ maxn) {
    __shared__ __align__(16) __hip_bfloat16 T[64][72];
    const int blk = blockIdx.x;
    const int b  = blk >> 7;
    const int n0 = (blk & 127) << 6;
    const int tid = threadIdx.x;

#pragma unroll
    for (int v = 0; v < 2; ++v) {
        const int vid = tid + (v << 8);          // 0..511
        const int row = vid >> 3;                // 0..63
        const int cb  = (vid & 7) << 3;          // 0,8,...,56
        const float* src = x + (((size_t)(b * NN + n0 + row)) << 6) + cb;
        float4 f0 = *(const float4*)(src);
        float4 f1 = *(const float4*)(src + 4);
        __align__(16) __hip_bfloat16 h[8];
        h[0] = __float2bfloat16(f0.x); h[1] = __float2bfloat16(f0.y);
        h[2] = __float2bfloat16(f0.z); h[3] = __float2bfloat16(f0.w);
        h[4] = __float2bfloat16(f1.x); h[5] = __float2bfloat16(f1.y);
        h[6] = __float2bfloat16(f1.z); h[7] = __float2bfloat16(f1.w);
        *(int4v*)(qb + (((size_t)(b * NN + n0 + row)) << 6) + cb) = *(const int4v*)h;
        *(int4v*)(&T[row][cb]) = *(const int4v*)h;
    }
    __syncthreads();
#pragma unroll
    for (int v = 0; v < 2; ++v) {
        const int vid = tid + (v << 8);
        const int c  = vid >> 3;                 // 0..63
        const int nb = (vid & 7) << 3;           // 0..56
        __align__(16) __hip_bfloat16 h[8];
#pragma unroll
        for (int j = 0; j < 8; ++j) h[j] = T[nb + j][c];
        *(int4v*)(qt + (((size_t)(b * NC + c)) << 13) + n0 + nb) = *(const int4v*)h;
    }
    // per-row norms of the bf16-quantized rows -> per-batch max
    if (tid < 64) {
        float s = 0.f;
        for (int c = 0; c < 64; ++c) {
            float v = __bfloat162float(T[tid][c]);
            s += v * v;
        }
        atomicMax(&maxn[b], __float_as_uint(sqrtf(s)));
    }
}

// ---------------- main: flash attention, fixed per-row softmax bound ----------------
__global__ __launch_bounds__(256) void attn_kernel(
        const float* __restrict__ x,
        const float* __restrict__ gamma_p,
        const __hip_bfloat16* __restrict__ qb,
        const __hip_bfloat16* __restrict__ qt,
        const unsigned int* __restrict__ maxn,
        float* __restrict__ out) {
    __shared__ __align__(16) __hip_bfloat16 KVs[64][72];  // key rows x c
    __shared__ __align__(16) __hip_bfloat16 KVt[64][72];  // c rows x key
    __shared__ __align__(16) __hip_bfloat16 Ps[64][72];   // q rows x key (also Q staging)

    const int blk = blockIdx.x;
    const int b  = blk >> 7;
    const int q0 = (blk & 127) << 6;
    const int tid  = threadIdx.x;
    const int wave = tid >> 6;
    const int lane = tid & 63;
    const int g    = lane >> 4;      // quad
    const int r16  = lane & 15;

    const __hip_bfloat16* kvptr = qb + ((size_t)b << 19);  // b*8192*64
    const __hip_bfloat16* ktptr = qt + ((size_t)b << 19);  // b*64*8192

    // ---- stage Q tile into Ps (reused later for P)
#pragma unroll
    for (int v = 0; v < 2; ++v) {
        const int vid = tid + (v << 8);
        const int row = vid >> 3;
        const int cb  = (vid & 7) << 3;
        int4v d = *(const int4v*)(kvptr + (((size_t)(q0 + row)) << 6) + cb);
        *(int4v*)(&Ps[row][cb]) = d;
    }
    __syncthreads();

    // Q A-fragments, kept in registers for the whole kernel.
    // A layout: A[m = lane&15][k = g*8+j]; row = wave*16 + r16
    bf16x8 aQ0 = *(const bf16x8*)(&Ps[(wave << 4) + r16][(g << 3)]);
    bf16x8 aQ1 = *(const bf16x8*)(&Ps[(wave << 4) + r16][(g << 3) + 32]);

    // per-row softmax bound: mb = ||q_row|| * maxnorm(batch)
    float mbound[4];
    {
        float s = 0.f;
#pragma unroll
        for (int j = 0; j < 8; ++j) {
            float f = __uint_as_float(((unsigned int)(unsigned short)aQ0[j]) << 16);
            s += f * f;
        }
#pragma unroll
        for (int j = 0; j < 8; ++j) {
            float f = __uint_as_float(((unsigned int)(unsigned short)aQ1[j]) << 16);
            s += f * f;
        }
        s += __shfl_xor(s, 16);
        s += __shfl_xor(s, 32);                 // full row sumsq for row (wave*16 + r16)
        float mb_me = sqrtf(s) * __uint_as_float(maxn[b]);
        // C/D rows for this lane are g*4+r; fetch their bounds (held at lanes r16==g*4+r)
#pragma unroll
        for (int r = 0; r < 4; ++r) mbound[r] = __shfl(mb_me, (g << 2) + r);
    }

    f32x4 Oacc[4];
#pragma unroll
    for (int n0 = 0; n0 < 4; ++n0) Oacc[n0] = (f32x4)(0.f);
    f32x4 lacc = (f32x4)(0.f);

    for (int kt = 0; kt < 128; ++kt) {
        const int kb = kt << 6;
        __syncthreads();   // previous iteration's KV reads complete before overwrite
        // ---- stage KV tile (both layouts), coalesced 16B loads
#pragma unroll
        for (int v = 0; v < 2; ++v) {
            const int vid = tid + (v << 8);
            const int row = vid >> 3;
            const int cb  = (vid & 7) << 3;
            int4v d = *(const int4v*)(kvptr + (((size_t)(kb + row)) << 6) + cb);
            *(int4v*)(&KVs[row][cb]) = d;
            int4v dt = *(const int4v*)(ktptr + (((size_t)row) << 13) + kb + cb);
            *(int4v*)(&KVt[row][cb]) = dt;
        }
        __syncthreads();

        // ---- S = Q * K^T  (per wave: 16 rows x 64 keys)
        f32x4 S[4];
#pragma unroll
        for (int n0 = 0; n0 < 4; ++n0) {
            bf16x8 b0 = *(const bf16x8*)(&KVs[(n0 << 4) + r16][(g << 3)]);
            bf16x8 b1 = *(const bf16x8*)(&KVs[(n0 << 4) + r16][(g << 3) + 32]);
            f32x4 acc = (f32x4)(0.f);
            acc = __builtin_amdgcn_mfma_f32_16x16x32_bf16(aQ0, b0, acc, 0, 0, 0);
            acc = __builtin_amdgcn_mfma_f32_16x16x32_bf16(aQ1, b1, acc, 0, 0, 0);
            S[n0] = acc;
        }

        // ---- p = exp(S - mbound); accumulate l; write P (bf16) to LDS
#pragma unroll
        for (int n0 = 0; n0 < 4; ++n0) {
#pragma unroll
            for (int r = 0; r < 4; ++r) {
                float p = __expf(S[n0][r] - mbound[r]);
                lacc[r] += p;
                Ps[(wave << 4) + (g << 2) + r][(n0 << 4) + r16] = __float2bfloat16(p);
            }
        }

        // ---- P A-frags (wave-private rows; lgkmcnt ordering within wave)
        bf16x8 aP0 = *(const bf16x8*)(&Ps[(wave << 4) + r16][(g << 3)]);
        bf16x8 aP1 = *(const bf16x8*)(&Ps[(wave << 4) + r16][(g << 3) + 32]);

        // ---- O += P * V   (B[k=key][n=c] read from KVt[c][key])
#pragma unroll
        for (int n0 = 0; n0 < 4; ++n0) {
            bf16x8 b0 = *(const bf16x8*)(&KVt[(n0 << 4) + r16][(g << 3)]);
            bf16x8 b1 = *(const bf16x8*)(&KVt[(n0 << 4) + r16][(g << 3) + 32]);
            Oacc[n0] = __builtin_amdgcn_mfma_f32_16x16x32_bf16(aP0, b0, Oacc[n0], 0, 0, 0);
            Oacc[n0] = __builtin_amdgcn_mfma_f32_16x16x32_bf16(aP1, b1, Oacc[n0], 0, 0, 0);
        }
    }

    // ---- final l reduction across the 16 lanes of each quad-group
#pragma unroll
    for (int off = 1; off < 16; off <<= 1) {
        f32x4 o;
#pragma unroll
        for (int r = 0; r < 4; ++r) o[r] = __shfl_xor(lacc[r], off);
        lacc += o;
    }
    float invl[4];
#pragma unroll
    for (int r = 0; r < 4; ++r) invl[r] = 1.0f / lacc[r];

    const float gm = gamma_p[0];
#pragma unroll
    for (int n0 = 0; n0 < 4; ++n0) {
#pragma unroll
        for (int r = 0; r < 4; ++r) {
            const int row = q0 + (wave << 4) + (g << 2) + r;
            const int col = (n0 << 4) + r16;
            const size_t idx = (((size_t)(b * NN + row)) << 6) + col;
            out[idx] = gm * (Oacc[n0][r] * invl[r]) + x[idx];
        }
    }
}

extern "C" void kernel_launch(void* const* d_in, const int* in_sizes, int n_in,
                              void* d_out, int out_size, void* d_ws, size_t ws_size,
                              hipStream_t stream) {
    const float* x     = (const float*)d_in[0];
    const float* gamma = (const float*)d_in[1];
    float* out = (float*)d_out;

    __hip_bfloat16* qb = (__hip_bfloat16*)d_ws;
    __hip_bfloat16* qt = qb + (size_t)NB * NN * NC;                 // +2MB
    unsigned int* maxn = (unsigned int*)((char*)d_ws + (size_t)4 * 1024 * 1024);

    hipMemsetAsync(maxn, 0, 2 * sizeof(unsigned int), stream);
    prep_kernel<<<256, 256, 0, stream>>>(x, qb, qt, maxn);
    attn_kernel<<<256, 256, 0, stream>>>(x, gamma, qb, qt, maxn, out);
}

// Round 2
// 142.820 us; speedup vs baseline: 1.9580x; 1.9580x over previous
//
#include <hip/hip_runtime.h>
#include <hip/hip_bf16.h>

typedef __attribute__((ext_vector_type(8))) short bf16x8;
typedef __attribute__((ext_vector_type(4))) float f32x4;
typedef __attribute__((ext_vector_type(4))) int int4v;

#define NB 2
#define NN 8192
#define NC 64
#define SPLIT 4
#define KT_PER (128 / SPLIT)   // 32 key-tiles of 64 per chunk

// ws layout (bytes):
//   [0, 2MB)        qb : bf16 [B][N][C]
//   [2MB, 4MB)      qt : bf16 [B][C][N]
//   [4MB, 4MB+8)    maxn : uint32[2]
//   [4MB+256, +16MB) opart : fp32 [SPLIT][B][N][C]
//   [20MB+256, ...)  lpart : fp32 [SPLIT][B][N]

// ---------------- prep: fp32 -> bf16 row-major + transposed + row-norm max ----------------
__global__ __launch_bounds__(256) void prep_kernel(
        const float* __restrict__ x,
        __hip_bfloat16* __restrict__ qb,
        __hip_bfloat16* __restrict__ qt,
        unsigned int* __restrict__ maxn) {
    __shared__ __align__(16) __hip_bfloat16 T[64][72];
    const int blk = blockIdx.x;
    const int b  = blk >> 7;
    const int n0 = (blk & 127) << 6;
    const int tid = threadIdx.x;

#pragma unroll
    for (int v = 0; v < 2; ++v) {
        const int vid = tid + (v << 8);          // 0..511
        const int row = vid >> 3;                // 0..63
        const int cb  = (vid & 7) << 3;          // 0,8,...,56
        const float* src = x + (((size_t)(b * NN + n0 + row)) << 6) + cb;
        float4 f0 = *(const float4*)(src);
        float4 f1 = *(const float4*)(src + 4);
        __align__(16) __hip_bfloat16 h[8];
        h[0] = __float2bfloat16(f0.x); h[1] = __float2bfloat16(f0.y);
        h[2] = __float2bfloat16(f0.z); h[3] = __float2bfloat16(f0.w);
        h[4] = __float2bfloat16(f1.x); h[5] = __float2bfloat16(f1.y);
        h[6] = __float2bfloat16(f1.z); h[7] = __float2bfloat16(f1.w);
        *(int4v*)(qb + (((size_t)(b * NN + n0 + row)) << 6) + cb) = *(const int4v*)h;
        *(int4v*)(&T[row][cb]) = *(const int4v*)h;
    }
    __syncthreads();
#pragma unroll
    for (int v = 0; v < 2; ++v) {
        const int vid = tid + (v << 8);
        const int c  = vid >> 3;                 // 0..63
        const int nb = (vid & 7) << 3;           // 0..56
        __align__(16) __hip_bfloat16 h[8];
#pragma unroll
        for (int j = 0; j < 8; ++j) h[j] = T[nb + j][c];
        *(int4v*)(qt + (((size_t)(b * NC + c)) << 13) + n0 + nb) = *(const int4v*)h;
    }
    if (tid < 64) {
        float s = 0.f;
        for (int c = 0; c < 64; ++c) {
            float v = __bfloat162float(T[tid][c]);
            s += v * v;
        }
        atomicMax(&maxn[b], __float_as_uint(sqrtf(s)));
    }
}

// ---------------- main: flash attention, fixed-bound softmax, K-split ----------------
// Fixed per-row bound => partial (O,l) over disjoint key ranges are additive.
__global__ __launch_bounds__(256, 4) void attn_kernel(
        const __hip_bfloat16* __restrict__ qb,
        const __hip_bfloat16* __restrict__ qt,
        const unsigned int* __restrict__ maxn,
        float* __restrict__ opart,
        float* __restrict__ lpart) {
    __shared__ __align__(16) __hip_bfloat16 KVs[64][72];  // key rows x c
    __shared__ __align__(16) __hip_bfloat16 KVt[64][72];  // c rows x key
    __shared__ __align__(16) __hip_bfloat16 Ps[64][72];   // q rows x key (also Q staging)

    const int blk   = blockIdx.x;
    const int chunk = blk & (SPLIT - 1);
    const int qt_i  = (blk >> 2) & 127;
    const int b     = blk >> 9;
    const int q0    = qt_i << 6;
    const int tid  = threadIdx.x;
    const int wave = tid >> 6;
    const int lane = tid & 63;
    const int g    = lane >> 4;      // quad
    const int r16  = lane & 15;

    const __hip_bfloat16* kvptr = qb + ((size_t)b << 19);  // b*8192*64
    const __hip_bfloat16* ktptr = qt + ((size_t)b << 19);  // b*64*8192

    // ---- stage Q tile into Ps (reused later for P)
#pragma unroll
    for (int v = 0; v < 2; ++v) {
        const int vid = tid + (v << 8);
        const int row = vid >> 3;
        const int cb  = (vid & 7) << 3;
        int4v d = *(const int4v*)(kvptr + (((size_t)(q0 + row)) << 6) + cb);
        *(int4v*)(&Ps[row][cb]) = d;
    }
    __syncthreads();

    // Q A-fragments, kept in registers. A[m=lane&15][k=g*8+j]; row = wave*16 + r16
    bf16x8 aQ0 = *(const bf16x8*)(&Ps[(wave << 4) + r16][(g << 3)]);
    bf16x8 aQ1 = *(const bf16x8*)(&Ps[(wave << 4) + r16][(g << 3) + 32]);

    // per-row softmax bound: mb = ||q_row|| * maxnorm(batch)  (identical across chunks)
    float mbound[4];
    {
        float s = 0.f;
#pragma unroll
        for (int j = 0; j < 8; ++j) {
            float f = __uint_as_float(((unsigned int)(unsigned short)aQ0[j]) << 16);
            s += f * f;
        }
#pragma unroll
        for (int j = 0; j < 8; ++j) {
            float f = __uint_as_float(((unsigned int)(unsigned short)aQ1[j]) << 16);
            s += f * f;
        }
        s += __shfl_xor(s, 16);
        s += __shfl_xor(s, 32);
        float mb_me = sqrtf(s) * __uint_as_float(maxn[b]);
#pragma unroll
        for (int r = 0; r < 4; ++r) mbound[r] = __shfl(mb_me, (g << 2) + r);
    }

    f32x4 Oacc[4];
#pragma unroll
    for (int n0 = 0; n0 < 4; ++n0) Oacc[n0] = (f32x4)(0.f);
    f32x4 lacc = (f32x4)(0.f);

    for (int kt = chunk * KT_PER; kt < (chunk + 1) * KT_PER; ++kt) {
        const int kb = kt << 6;
        __syncthreads();   // previous iteration's KV reads complete before overwrite
#pragma unroll
        for (int v = 0; v < 2; ++v) {
            const int vid = tid + (v << 8);
            const int row = vid >> 3;
            const int cb  = (vid & 7) << 3;
            int4v d = *(const int4v*)(kvptr + (((size_t)(kb + row)) << 6) + cb);
            *(int4v*)(&KVs[row][cb]) = d;
            int4v dt = *(const int4v*)(ktptr + (((size_t)row) << 13) + kb + cb);
            *(int4v*)(&KVt[row][cb]) = dt;
        }
        __syncthreads();

        // ---- S = Q * K^T  (per wave: 16 rows x 64 keys)
        f32x4 S[4];
#pragma unroll
        for (int n0 = 0; n0 < 4; ++n0) {
            bf16x8 b0 = *(const bf16x8*)(&KVs[(n0 << 4) + r16][(g << 3)]);
            bf16x8 b1 = *(const bf16x8*)(&KVs[(n0 << 4) + r16][(g << 3) + 32]);
            f32x4 acc = (f32x4)(0.f);
            acc = __builtin_amdgcn_mfma_f32_16x16x32_bf16(aQ0, b0, acc, 0, 0, 0);
            acc = __builtin_amdgcn_mfma_f32_16x16x32_bf16(aQ1, b1, acc, 0, 0, 0);
            S[n0] = acc;
        }

        // ---- p = exp(S - mbound); accumulate l; write P (bf16) to LDS
#pragma unroll
        for (int n0 = 0; n0 < 4; ++n0) {
#pragma unroll
            for (int r = 0; r < 4; ++r) {
                float p = __expf(S[n0][r] - mbound[r]);
                lacc[r] += p;
                Ps[(wave << 4) + (g << 2) + r][(n0 << 4) + r16] = __float2bfloat16(p);
            }
        }

        // ---- P A-frags (wave-private rows)
        bf16x8 aP0 = *(const bf16x8*)(&Ps[(wave << 4) + r16][(g << 3)]);
        bf16x8 aP1 = *(const bf16x8*)(&Ps[(wave << 4) + r16][(g << 3) + 32]);

        // ---- O += P * V
#pragma unroll
        for (int n0 = 0; n0 < 4; ++n0) {
            bf16x8 b0 = *(const bf16x8*)(&KVt[(n0 << 4) + r16][(g << 3)]);
            bf16x8 b1 = *(const bf16x8*)(&KVt[(n0 << 4) + r16][(g << 3) + 32]);
            Oacc[n0] = __builtin_amdgcn_mfma_f32_16x16x32_bf16(aP0, b0, Oacc[n0], 0, 0, 0);
            Oacc[n0] = __builtin_amdgcn_mfma_f32_16x16x32_bf16(aP1, b1, Oacc[n0], 0, 0, 0);
        }
    }

    // ---- l reduction across the 16 lanes of each quad-group
#pragma unroll
    for (int off = 1; off < 16; off <<= 1) {
        f32x4 o;
#pragma unroll
        for (int r = 0; r < 4; ++r) o[r] = __shfl_xor(lacc[r], off);
        lacc += o;
    }

    // ---- store partials (raw sums; finalize combines chunks)
    float* ochunk = opart + ((size_t)chunk << 20);   // chunk * 2*8192*64
#pragma unroll
    for (int n0 = 0; n0 < 4; ++n0) {
#pragma unroll
        for (int r = 0; r < 4; ++r) {
            const int row = q0 + (wave << 4) + (g << 2) + r;
            const int col = (n0 << 4) + r16;
            ochunk[(((size_t)(b * NN + row)) << 6) + col] = Oacc[n0][r];
        }
    }
    if (r16 == 0) {
#pragma unroll
        for (int r = 0; r < 4; ++r) {
            const int row = q0 + (wave << 4) + (g << 2) + r;
            lpart[(chunk << 14) + (b << 13) + row] = lacc[r];
        }
    }
}

// ---------------- finalize: out = gamma * (sum O)/(sum l) + x ----------------
__global__ __launch_bounds__(256) void finalize_kernel(
        const float* __restrict__ x,
        const float* __restrict__ gamma_p,
        const float* __restrict__ opart,
        const float* __restrict__ lpart,
        float* __restrict__ out) {
    const int i4 = blockIdx.x * 256 + threadIdx.x;   // 0..262143 float4s
    const size_t e = (size_t)i4 << 2;
    const int rowg = i4 >> 4;                        // global row 0..16383

    float l = 0.f;
#pragma unroll
    for (int c = 0; c < SPLIT; ++c) l += lpart[(c << 14) + rowg];

    float4 o = make_float4(0.f, 0.f, 0.f, 0.f);
#pragma unroll
    for (int c = 0; c < SPLIT; ++c) {
        float4 t = *(const float4*)(opart + ((size_t)c << 20) + e);
        o.x += t.x; o.y += t.y; o.z += t.z; o.w += t.w;
    }
    const float inv = 1.0f / l;
    const float gm = gamma_p[0];
    float4 xin = *(const float4*)(x + e);
    float4 r;
    r.x = gm * (o.x * inv) + xin.x;
    r.y = gm * (o.y * inv) + xin.y;
    r.z = gm * (o.z * inv) + xin.z;
    r.w = gm * (o.w * inv) + xin.w;
    *(float4*)(out + e) = r;
}

extern "C" void kernel_launch(void* const* d_in, const int* in_sizes, int n_in,
                              void* d_out, int out_size, void* d_ws, size_t ws_size,
                              hipStream_t stream) {
    const float* x     = (const float*)d_in[0];
    const float* gamma = (const float*)d_in[1];
    float* out = (float*)d_out;

    __hip_bfloat16* qb = (__hip_bfloat16*)d_ws;
    __hip_bfloat16* qt = qb + (size_t)NB * NN * NC;                       // +2MB
    unsigned int* maxn = (unsigned int*)((char*)d_ws + (size_t)4 * 1024 * 1024);
    float* opart = (float*)((char*)d_ws + (size_t)4 * 1024 * 1024 + 256); // 16MB
    float* lpart = opart + (size_t)SPLIT * NB * NN * NC;                  // 256KB

    hipMemsetAsync(maxn, 0, 2 * sizeof(unsigned int), stream);
    prep_kernel<<<256, 256, 0, stream>>>(x, qb, qt, maxn);
    attn_kernel<<<NB * 128 * SPLIT, 256, 0, stream>>>(qb, qt, maxn, opart, lpart);
    finalize_kernel<<<(NB * NN * NC / 4) / 256, 256, 0, stream>>>(x, gamma, opart, lpart, out);
}